// Round 3
// baseline (113.654 us; speedup 1.0000x reference)
//
#include <hip/hip_runtime.h>

// AffinityLoss: logits (2,19,384,384) fp32, labels (2,384,384) int32 -> scalar fp32.
// R5: single fused kernel (last-block-done reduction) — removes the finalize
// dispatch + inter-kernel drain. Ticket counter in d_ws zeroed by a 4-byte
// hipMemsetAsync (d_ws is re-poisoned each iteration, so no self-reset trick).
// Cross-XCD visibility per G16: release __threadfence + device-scope ticket
// atomicAdd; acquire fence + agent-scope loads in the last block.
// Compute core unchanged from R4 (passed, absmax 0): CS=20 b128 LDS tiles,
// hw-softplus, pairwise neighbor ILP, f32 accum -> double per block.

#define IGNORE_INDEX (-100)

constexpr int Hh = 384, Ww = 384, Cc = 19;
constexpr int HW = Hh * Ww;                  // 147456
constexpr int HP = 382, WP = 382;            // h-k+1, w-k+1
constexpr int TX = 32, TY = 8;               // pixel tile per block
constexpr int NT = TX * TY;                  // 256 threads = 4 waves
constexpr int LXX = TX + 4;                  // halo: dx in [-2,2] -> 36
constexpr int LYY = TY + 2;                  // halo: dy in [0,2]  -> 10
constexpr int CS  = 20;                      // padded channel stride (floats)
constexpr int NBX = Ww / TX, NBY = Hh / TY;  // 12, 48
constexpr int NBLK = NBX * NBY * 2;          // 1152

__device__ __forceinline__ int mult_y(int y, int di) {
    int lo = y - (HP - 1); if (lo < 0) lo = 0;
    int hi = 2 - di;       if (y < hi) hi = y;
    int c = hi - lo + 1;   return c > 0 ? c : 0;
}
__device__ __forceinline__ int mult_x(int x, int dj) {
    int lo = (-dj > 0) ? -dj : 0;
    int lo2 = x - (WP - 1); if (lo2 > lo) lo = lo2;
    int hi = (2 - dj < 2) ? (2 - dj) : 2;
    if (x < hi) hi = x;
    int c = hi - lo + 1;   return c > 0 ? c : 0;
}

// softplus(t) = max(t,0) + ln2*log2(1 + 2^(-|t|*log2e))
__device__ __forceinline__ float softplus(float t) {
    float e = __builtin_amdgcn_exp2f(-1.4426950408889634f * fabsf(t));
    float l = __builtin_amdgcn_logf(1.0f + e);
    return fmaxf(t, 0.0f) + 0.6931471805599453f * l;
}

__global__ __launch_bounds__(NT, 4) void aff_loss_kernel(
        const float* __restrict__ logits, const int* __restrict__ labels,
        unsigned* __restrict__ ticket, double* __restrict__ partial,
        float* __restrict__ out) {
    __shared__ __align__(16) float sv[LYY * LXX * CS];  // [entry][c], stride 20
    __shared__ int   sl[LYY * LXX];
    __shared__ float sred[NT / 64];
    __shared__ int   lastflag;

    const int n   = blockIdx.z;
    const int tx0 = blockIdx.x * TX;
    const int ty0 = blockIdx.y * TY;
    const int tid = threadIdx.x;
    const int bid = (blockIdx.z * NBY + blockIdx.y) * NBX + blockIdx.x;

    const float* img = logits + (size_t)n * Cc * HW;
    const int*   lab = labels + (size_t)n * HW;

    // stage tile + halo (border-clamped entries only used with multiplicity 0)
    for (int idx = tid; idx < LYY * LXX; idx += NT) {
        int r = idx / LXX, col = idx - r * LXX;
        int gy = ty0 + r;       if (gy > Hh - 1) gy = Hh - 1;
        int gx = tx0 + col - 2; if (gx < 0) gx = 0; if (gx > Ww - 1) gx = Ww - 1;
        sl[idx] = lab[gy * Ww + gx];
        const float* s = img + gy * Ww + gx;
        float4 t0, t1, t2, t3, t4;
        t0.x = s[0 * HW];  t0.y = s[1 * HW];  t0.z = s[2 * HW];  t0.w = s[3 * HW];
        t1.x = s[4 * HW];  t1.y = s[5 * HW];  t1.z = s[6 * HW];  t1.w = s[7 * HW];
        t2.x = s[8 * HW];  t2.y = s[9 * HW];  t2.z = s[10 * HW]; t2.w = s[11 * HW];
        t3.x = s[12 * HW]; t3.y = s[13 * HW]; t3.z = s[14 * HW]; t3.w = s[15 * HW];
        t4.x = s[16 * HW]; t4.y = s[17 * HW]; t4.z = s[18 * HW]; t4.w = 0.0f;
        float4* dst = reinterpret_cast<float4*>(&sv[idx * CS]);
        dst[0] = t0; dst[1] = t1; dst[2] = t2; dst[3] = t3; dst[4] = t4;
    }
    __syncthreads();

    const int tx = tid & (TX - 1), ty = tid >> 5;   // TX == 32
    const int x = tx0 + tx, y = ty0 + ty;
    const int ep = ty * LXX + (tx + 2);

    const float4* P = reinterpret_cast<const float4*>(&sv[ep * CS]);
    const float4 p0 = P[0], p1 = P[1], p2 = P[2], p3 = P[3], p4 = P[4];
    const int lp = sl[ep];
    const bool vp = (lp != IGNORE_INDEX);

    // float multiplicity weights: rows dy in {0,1,2}, cols dj in {-2..2}
    // off-diagonal weight 2*my*mx: fold the 2 into mxf2.
    float myf[3], mxf2[5];
    #pragma unroll
    for (int i = 0; i < 3; ++i) myf[i] = (float)mult_y(y, i);
    #pragma unroll
    for (int j = 0; j < 5; ++j) mxf2[j] = 2.0f * (float)mult_x(x, j - 2);

    auto dot19 = [&](float4 b0, float4 b1, float4 b2, float4 b3, float4 b4) {
        float xa = p0.x * b0.x, xb = p0.y * b0.y;
        xa = fmaf(p0.z, b0.z, xa); xb = fmaf(p0.w, b0.w, xb);
        xa = fmaf(p1.x, b1.x, xa); xb = fmaf(p1.y, b1.y, xb);
        xa = fmaf(p1.z, b1.z, xa); xb = fmaf(p1.w, b1.w, xb);
        xa = fmaf(p2.x, b2.x, xa); xb = fmaf(p2.y, b2.y, xb);
        xa = fmaf(p2.z, b2.z, xa); xb = fmaf(p2.w, b2.w, xb);
        xa = fmaf(p3.x, b3.x, xa); xb = fmaf(p3.y, b3.y, xb);
        xa = fmaf(p3.z, b3.z, xa); xb = fmaf(p3.w, b3.w, xb);
        xa = fmaf(p4.x, b4.x, xa); xb = fmaf(p4.y, b4.y, xb);
        xa = fmaf(p4.z, b4.z, xa);
        return xa + xb;
    };

    float tsum;
    // diagonal (b == p): weight my[0]*mx[0] = 0.5*myf[0]*mxf2[2]
    {
        float xd = dot19(p0, p1, p2, p3, p4);
        float t = vp ? -xd : xd;
        tsum = (0.5f * myf[0] * mxf2[2]) * softplus(t);
    }

    const int DY[12] = {0, 0, 1, 1, 1, 1, 1, 2, 2, 2, 2, 2};
    const int DX[12] = {1, 2, -2, -1, 0, 1, 2, -2, -1, 0, 1, 2};
    #pragma unroll
    for (int dd = 0; dd < 12; dd += 2) {
        const int dy0 = DY[dd], dx0 = DX[dd];
        const int dy1 = DY[dd + 1], dx1 = DX[dd + 1];
        const int eq0 = (ty + dy0) * LXX + (tx + 2 + dx0);
        const int eq1 = (ty + dy1) * LXX + (tx + 2 + dx1);
        const float4* Q0 = reinterpret_cast<const float4*>(&sv[eq0 * CS]);
        const float4* Q1 = reinterpret_cast<const float4*>(&sv[eq1 * CS]);
        float4 a0 = Q0[0], a1 = Q0[1], a2 = Q0[2], a3 = Q0[3], a4 = Q0[4];
        float4 c0 = Q1[0], c1 = Q1[1], c2 = Q1[2], c3 = Q1[3], c4 = Q1[4];
        const int lq0 = sl[eq0], lq1 = sl[eq1];
        const float x0 = dot19(a0, a1, a2, a3, a4);
        const float x1 = dot19(c0, c1, c2, c3, c4);
        const float t0 = (vp && lq0 == lp) ? -x0 : x0;
        const float t1 = (vp && lq1 == lp) ? -x1 : x1;
        tsum = fmaf(myf[dy0] * mxf2[dx0 + 2], softplus(t0), tsum);
        tsum = fmaf(myf[dy1] * mxf2[dx1 + 2], softplus(t1), tsum);
    }

    // block reduce: f32 wave shuffle -> LDS -> double block sum
    for (int off = 32; off > 0; off >>= 1) tsum += __shfl_down(tsum, off, 64);
    if ((tid & 63) == 0) sred[tid >> 6] = tsum;
    __syncthreads();

    // publish partial + take a ticket; last block reduces all partials
    if (tid == 0) {
        double s = 0.0;
        #pragma unroll
        for (int i = 0; i < NT / 64; ++i) s += (double)sred[i];
        partial[bid] = s;
        __threadfence();                       // release: partial visible device-wide
        unsigned t = atomicAdd(ticket, 1u);    // device scope
        lastflag = (t == NBLK - 1) ? 1 : 0;
    }
    __syncthreads();

    if (lastflag) {
        __threadfence();                       // acquire side
        double s = 0.0;
        for (int i = tid; i < NBLK; i += NT)
            s += __hip_atomic_load(&partial[i], __ATOMIC_RELAXED,
                                   __HIP_MEMORY_SCOPE_AGENT);
        // double wave reduce via two 32-bit shuffles per step
        for (int off = 32; off > 0; off >>= 1) s += __shfl_down(s, off, 64);
        __shared__ double dred[NT / 64];
        if ((tid & 63) == 0) dred[tid >> 6] = s;
        __syncthreads();
        if (tid == 0) {
            double tot = 0.0;
            #pragma unroll
            for (int i = 0; i < NT / 64; ++i) tot += dred[i];
            // mean over n*9*9*L = 2*81*382*382 = 23,639,688 terms
            out[0] = (float)(tot * (1.0 / 23639688.0));
        }
    }
}

extern "C" void kernel_launch(void* const* d_in, const int* in_sizes, int n_in,
                              void* d_out, int out_size, void* d_ws, size_t ws_size,
                              hipStream_t stream) {
    const float* logits = (const float*)d_in[0];
    const int*   labels = (const int*)d_in[1];
    float* out = (float*)d_out;
    unsigned* ticket = (unsigned*)d_ws;               // slot 0 (8B reserved)
    double* partial = (double*)d_ws + 1;              // slots 1..NBLK

    hipMemsetAsync(d_ws, 0, 4, stream);               // zero the ticket only
    dim3 grid(NBX, NBY, 2);   // 12 x 48 x 2 = 1152 blocks
    aff_loss_kernel<<<grid, NT, 0, stream>>>(logits, labels, ticket, partial, out);
}

// Round 5
// 89.032 us; speedup vs baseline: 1.2766x; 1.2766x over previous
//
#include <hip/hip_runtime.h>

// AffinityLoss: logits (2,19,384,384) fp32, labels (2,384,384) int32 -> scalar fp32.
// R7: attack the staging DRAM pattern (the ~25us that survived every compute
// change). Evidence: aff FETCH=41MB at ~1.3TB/s effective; the 256MB d_ws
// poison fill evicts L3 every iteration, so logits re-fetch from HBM with
// 576KB-strided fine-grained reads (DRAM row thrash). Fix:
//   K1 repack: NCHW -> [n][y][x][c-pad20] f32 via LDS transpose
//      (contiguous streaming reads, contiguous coalesced writes, ~48MB BW).
//   K2 aff: R2's verified core unchanged, staging now reads contiguous
//      2.9KB/row spans (5x dwordx4 per entry) from the repacked buffer.
//   K3 finalize: as R2.
// Cooperative launch (R6) failed under graph capture — never again.
// Ticket fusion (R3) cost +12us — keep separate finalize.

#define IGNORE_INDEX (-100)

constexpr int Hh = 384, Ww = 384, Cc = 19;
constexpr int HW = Hh * Ww;                  // 147456
constexpr int HP = 382, WP = 382;            // h-k+1, w-k+1
constexpr int TX = 32, TY = 8;               // pixel tile per block
constexpr int NT = TX * TY;                  // 256 threads = 4 waves
constexpr int LXX = TX + 4;                  // halo: dx in [-2,2] -> 36
constexpr int LYY = TY + 2;                  // halo: dy in [0,2]  -> 10
constexpr int CS  = 20;                      // padded channel stride (floats)
constexpr int NBX = Ww / TX, NBY = Hh / TY;  // 12, 48
constexpr int NBLK = NBX * NBY * 2;          // 1152

// repack tile
constexpr int AY = 4, AX = 64;               // 4 rows x 64 cols, 256 threads
constexpr int ACS = 21;                      // LDS channel stride (odd -> 2-way max)

__device__ __forceinline__ int mult_y(int y, int di) {
    int lo = y - (HP - 1); if (lo < 0) lo = 0;
    int hi = 2 - di;       if (y < hi) hi = y;
    int c = hi - lo + 1;   return c > 0 ? c : 0;
}
__device__ __forceinline__ int mult_x(int x, int dj) {
    int lo = (-dj > 0) ? -dj : 0;
    int lo2 = x - (WP - 1); if (lo2 > lo) lo = lo2;
    int hi = (2 - dj < 2) ? (2 - dj) : 2;
    if (x < hi) hi = x;
    int c = hi - lo + 1;   return c > 0 ? c : 0;
}

// softplus(t) = max(t,0) + ln2*log2(1 + 2^(-|t|*log2e))
__device__ __forceinline__ float softplus(float t) {
    float e = __builtin_amdgcn_exp2f(-1.4426950408889634f * fabsf(t));
    float l = __builtin_amdgcn_logf(1.0f + e);
    return fmaxf(t, 0.0f) + 0.6931471805599453f * l;
}

// ---- K1: NCHW -> [n][y][x][c-pad20], exact f32 copy -------------------------
__global__ __launch_bounds__(256) void repack_kernel(
        const float* __restrict__ logits, float* __restrict__ rp) {
    __shared__ float sA[AY * AX * ACS];      // [row][col][c], stride 21
    const int n  = blockIdx.z;
    const int y0 = blockIdx.y * AY;
    const int x0 = blockIdx.x * AX;
    const int tid = threadIdx.x;
    const float* img = logits + (size_t)n * Cc * HW;

    // read: 19 c-planes x 4 rows x 16 seg = 1216 dwordx4, contiguous per (c,row)
    for (int task = tid; task < Cc * AY * 16; task += 256) {
        const int c = task >> 6;             // task / 64
        const int j = task & 63;
        const int row = j >> 4, seg = j & 15;
        const float4 v = *reinterpret_cast<const float4*>(
            img + ((size_t)c * Hh + (y0 + row)) * Ww + x0 + seg * 4);
        float* d = &sA[((row * AX) + seg * 4) * ACS + c];
        d[0 * ACS] = v.x; d[1 * ACS] = v.y; d[2 * ACS] = v.z; d[3 * ACS] = v.w;
    }
    __syncthreads();

    // write: one thread per pixel, 80B contiguous per pixel, wave = 5KB span
    const int row = tid >> 6, sx = tid & 63;
    const float* sp = &sA[(row * AX + sx) * ACS];
    float4 t0, t1, t2, t3, t4;
    t0.x = sp[0];  t0.y = sp[1];  t0.z = sp[2];  t0.w = sp[3];
    t1.x = sp[4];  t1.y = sp[5];  t1.z = sp[6];  t1.w = sp[7];
    t2.x = sp[8];  t2.y = sp[9];  t2.z = sp[10]; t2.w = sp[11];
    t3.x = sp[12]; t3.y = sp[13]; t3.z = sp[14]; t3.w = sp[15];
    t4.x = sp[16]; t4.y = sp[17]; t4.z = sp[18]; t4.w = 0.0f;
    float4* dst = reinterpret_cast<float4*>(
        rp + ((size_t)n * HW + (size_t)(y0 + row) * Ww + (x0 + sx)) * CS);
    dst[0] = t0; dst[1] = t1; dst[2] = t2; dst[3] = t3; dst[4] = t4;
}

// ---- K2: affinity loss from repacked buffer --------------------------------
__global__ __launch_bounds__(NT, 4) void aff_loss_kernel(
        const float* __restrict__ rp, const int* __restrict__ labels,
        double* __restrict__ partial) {
    __shared__ __align__(16) float sv[LYY * LXX * CS];  // [entry][c], stride 20
    __shared__ int   sl[LYY * LXX];
    __shared__ float sred[NT / 64];

    const int n   = blockIdx.z;
    const int tx0 = blockIdx.x * TX;
    const int ty0 = blockIdx.y * TY;
    const int tid = threadIdx.x;
    const int bid = (blockIdx.z * NBY + blockIdx.y) * NBX + blockIdx.x;

    const float* src = rp + (size_t)n * HW * CS;
    const int*   lab = labels + (size_t)n * HW;

    // stage tile + halo: contiguous 80B per entry (clamped entries -> mult 0)
    for (int idx = tid; idx < LYY * LXX; idx += NT) {
        int r = idx / LXX, col = idx - r * LXX;
        int gy = ty0 + r;       if (gy > Hh - 1) gy = Hh - 1;
        int gx = tx0 + col - 2; if (gx < 0) gx = 0; if (gx > Ww - 1) gx = Ww - 1;
        sl[idx] = lab[gy * Ww + gx];
        const float4* s = reinterpret_cast<const float4*>(
            src + ((size_t)gy * Ww + gx) * CS);
        float4* dst = reinterpret_cast<float4*>(&sv[idx * CS]);
        dst[0] = s[0]; dst[1] = s[1]; dst[2] = s[2]; dst[3] = s[3]; dst[4] = s[4];
    }
    __syncthreads();

    const int tx = tid & (TX - 1), ty = tid >> 5;   // TX == 32
    const int x = tx0 + tx, y = ty0 + ty;
    const int ep = ty * LXX + (tx + 2);

    const float4* P = reinterpret_cast<const float4*>(&sv[ep * CS]);
    const float4 p0 = P[0], p1 = P[1], p2 = P[2], p3 = P[3], p4 = P[4];
    const int lp = sl[ep];
    const bool vp = (lp != IGNORE_INDEX);

    float myf[3], mxf2[5];
    #pragma unroll
    for (int i = 0; i < 3; ++i) myf[i] = (float)mult_y(y, i);
    #pragma unroll
    for (int j = 0; j < 5; ++j) mxf2[j] = 2.0f * (float)mult_x(x, j - 2);

    auto dot19 = [&](float4 b0, float4 b1, float4 b2, float4 b3, float4 b4) {
        float xa = p0.x * b0.x, xb = p0.y * b0.y;
        xa = fmaf(p0.z, b0.z, xa); xb = fmaf(p0.w, b0.w, xb);
        xa = fmaf(p1.x, b1.x, xa); xb = fmaf(p1.y, b1.y, xb);
        xa = fmaf(p1.z, b1.z, xa); xb = fmaf(p1.w, b1.w, xb);
        xa = fmaf(p2.x, b2.x, xa); xb = fmaf(p2.y, b2.y, xb);
        xa = fmaf(p2.z, b2.z, xa); xb = fmaf(p2.w, b2.w, xb);
        xa = fmaf(p3.x, b3.x, xa); xb = fmaf(p3.y, b3.y, xb);
        xa = fmaf(p3.z, b3.z, xa); xb = fmaf(p3.w, b3.w, xb);
        xa = fmaf(p4.x, b4.x, xa); xb = fmaf(p4.y, b4.y, xb);
        xa = fmaf(p4.z, b4.z, xa);
        return xa + xb;
    };

    float tsum;
    // diagonal (b == p): weight my[0]*mx[0] = 0.5*myf[0]*mxf2[2]
    {
        float xd = dot19(p0, p1, p2, p3, p4);
        float t = vp ? -xd : xd;
        tsum = (0.5f * myf[0] * mxf2[2]) * softplus(t);
    }

    const int DY[12] = {0, 0, 1, 1, 1, 1, 1, 2, 2, 2, 2, 2};
    const int DX[12] = {1, 2, -2, -1, 0, 1, 2, -2, -1, 0, 1, 2};
    #pragma unroll
    for (int dd = 0; dd < 12; dd += 2) {
        const int dy0 = DY[dd], dx0 = DX[dd];
        const int dy1 = DY[dd + 1], dx1 = DX[dd + 1];
        const int eq0 = (ty + dy0) * LXX + (tx + 2 + dx0);
        const int eq1 = (ty + dy1) * LXX + (tx + 2 + dx1);
        const float4* Q0 = reinterpret_cast<const float4*>(&sv[eq0 * CS]);
        const float4* Q1 = reinterpret_cast<const float4*>(&sv[eq1 * CS]);
        float4 a0 = Q0[0], a1 = Q0[1], a2 = Q0[2], a3 = Q0[3], a4 = Q0[4];
        float4 c0 = Q1[0], c1 = Q1[1], c2 = Q1[2], c3 = Q1[3], c4 = Q1[4];
        const int lq0 = sl[eq0], lq1 = sl[eq1];
        const float x0 = dot19(a0, a1, a2, a3, a4);
        const float x1 = dot19(c0, c1, c2, c3, c4);
        const float t0 = (vp && lq0 == lp) ? -x0 : x0;
        const float t1 = (vp && lq1 == lp) ? -x1 : x1;
        tsum = fmaf(myf[dy0] * mxf2[dx0 + 2], softplus(t0), tsum);
        tsum = fmaf(myf[dy1] * mxf2[dx1 + 2], softplus(t1), tsum);
    }

    // reduce: f32 wave shuffle -> LDS -> one double store per block
    for (int off = 32; off > 0; off >>= 1) tsum += __shfl_down(tsum, off, 64);
    if ((tid & 63) == 0) sred[tid >> 6] = tsum;
    __syncthreads();
    if (tid == 0) {
        double s = 0.0;
        #pragma unroll
        for (int i = 0; i < NT / 64; ++i) s += (double)sred[i];
        partial[bid] = s;
    }
}

// ---- K3: finalize ----------------------------------------------------------
__global__ __launch_bounds__(256) void finalize_kernel(
        const double* __restrict__ partial, float* __restrict__ out) {
    __shared__ double sred[4];
    const int tid = threadIdx.x;
    double s = 0.0;
    for (int i = tid; i < NBLK; i += 256) s += partial[i];
    for (int off = 32; off > 0; off >>= 1) s += __shfl_down(s, off, 64);
    if ((tid & 63) == 0) sred[tid >> 6] = s;
    __syncthreads();
    if (tid == 0) {
        // mean over n*9*9*L = 2*81*382*382 = 23,639,688 terms
        double tot = sred[0] + sred[1] + sred[2] + sred[3];
        out[0] = (float)(tot * (1.0 / 23639688.0));
    }
}

extern "C" void kernel_launch(void* const* d_in, const int* in_sizes, int n_in,
                              void* d_out, int out_size, void* d_ws, size_t ws_size,
                              hipStream_t stream) {
    const float* logits = (const float*)d_in[0];
    const int*   labels = (const int*)d_in[1];
    float* out = (float*)d_out;
    float* rp = (float*)d_ws;                              // 23.6 MB repack
    double* partial = (double*)((char*)d_ws + (32u << 20)); // partials at +32MB

    dim3 gridA(Ww / AX, Hh / AY, 2);   // 6 x 96 x 2 = 1152 blocks
    repack_kernel<<<gridA, 256, 0, stream>>>(logits, rp);

    dim3 gridB(NBX, NBY, 2);           // 12 x 48 x 2 = 1152 blocks
    aff_loss_kernel<<<gridB, NT, 0, stream>>>(rp, labels, partial);

    finalize_kernel<<<1, 256, 0, stream>>>(partial, out);
}

// Round 6
// 74.792 us; speedup vs baseline: 1.5196x; 1.1904x over previous
//
#include <hip/hip_runtime.h>

// AffinityLoss: logits (2,19,384,384) fp32, labels (2,384,384) int32 -> scalar fp32.
// R8: T14 software pipeline across the two images. Evidence trail: aff is ~30us
// invariant to instruction count (R1), occupancy/ILP (R2), contiguous+L3-warm
// reads (R5) -> the exposed cost is the stage->barrier->compute latency chain,
// paid once per tile per image, with no overlap (compiler drains vmcnt(0) at
// every __syncthreads). Fix: 576 blocks, each does its tile for BOTH images:
//   load n0 -> regs; ds_write n0; barrier;
//   ISSUE n1 loads -> regs; compute n0 (hides n1 HBM latency);
//   barrier; ds_write n1; barrier; compute n1.
// Also: 8-XCD bijective block swizzle (576=8*72) so each XCD works one 48-row
// band (halo rows L2-local). Repack dropped (R5: no effect on aff).
// Math core bit-identical to R2 (passed, absmax 0).

#define IGNORE_INDEX (-100)

constexpr int Hh = 384, Ww = 384, Cc = 19;
constexpr int HW = Hh * Ww;                  // 147456
constexpr int HP = 382, WP = 382;            // h-k+1, w-k+1
constexpr int TX = 32, TY = 8;               // pixel tile per block
constexpr int NT = TX * TY;                  // 256 threads = 4 waves
constexpr int LXX = TX + 4;                  // halo: dx in [-2,2] -> 36
constexpr int LYY = TY + 2;                  // halo: dy in [0,2]  -> 10
constexpr int NE  = LYY * LXX;               // 360 staged entries
constexpr int CS  = 20;                      // padded channel stride (floats)
constexpr int NBX = Ww / TX, NBY = Hh / TY;  // 12, 48
constexpr int NBLK = NBX * NBY;              // 576 blocks (each does n=0,1)

__device__ __forceinline__ int mult_y(int y, int di) {
    int lo = y - (HP - 1); if (lo < 0) lo = 0;
    int hi = 2 - di;       if (y < hi) hi = y;
    int c = hi - lo + 1;   return c > 0 ? c : 0;
}
__device__ __forceinline__ int mult_x(int x, int dj) {
    int lo = (-dj > 0) ? -dj : 0;
    int lo2 = x - (WP - 1); if (lo2 > lo) lo = lo2;
    int hi = (2 - dj < 2) ? (2 - dj) : 2;
    if (x < hi) hi = x;
    int c = hi - lo + 1;   return c > 0 ? c : 0;
}

// softplus(t) = max(t,0) + ln2*log2(1 + 2^(-|t|*log2e))
__device__ __forceinline__ float softplus(float t) {
    float e = __builtin_amdgcn_exp2f(-1.4426950408889634f * fabsf(t));
    float l = __builtin_amdgcn_logf(1.0f + e);
    return fmaxf(t, 0.0f) + 0.6931471805599453f * l;
}

__global__ __launch_bounds__(NT, 4) void aff_loss_kernel(
        const float* __restrict__ logits, const int* __restrict__ labels,
        double* __restrict__ partial) {
    __shared__ __align__(16) float sv[NE * CS];  // [entry][c], stride 20
    __shared__ int   sl[NE];
    __shared__ float sred[NT / 64];

    // 8-XCD bijective swizzle: hw block i -> tile (i&7)*72 + (i>>3).
    // Each XCD gets 72 consecutive tiles = a 48-row band (halos L2-local).
    const int bid = ((int)blockIdx.x & 7) * (NBLK / 8) + ((int)blockIdx.x >> 3);
    const int bx = bid % NBX, by = bid / NBX;
    const int tx0 = bx * TX, ty0 = by * TY;
    const int tid = threadIdx.x;

    const int tx = tid & (TX - 1), ty = tid >> 5;   // TX == 32
    const int x = tx0 + tx, y = ty0 + ty;
    const int ep = ty * LXX + (tx + 2);

    // position-dependent (image-independent) multiplicity weights
    float myf[3], mxf2[5];
    #pragma unroll
    for (int i = 0; i < 3; ++i) myf[i] = (float)mult_y(y, i);
    #pragma unroll
    for (int j = 0; j < 5; ++j) mxf2[j] = 2.0f * (float)mult_x(x, j - 2);

    // each thread stages entry e0 = tid (all) and e1 = tid + NT (tid < 104)
    const int e0 = tid, e1 = tid + NT;
    const bool has2 = (e1 < NE);

    // global-load one staged entry into regs (19 floats + label), clamped
    auto load_entry = [&](const float* img, const int* lab, int idx,
                          float v[20], int& l) {
        int r = idx / LXX, col = idx - r * LXX;
        int gy = ty0 + r;       if (gy > Hh - 1) gy = Hh - 1;
        int gx = tx0 + col - 2; if (gx < 0) gx = 0; if (gx > Ww - 1) gx = Ww - 1;
        l = lab[gy * Ww + gx];
        const float* s = img + gy * Ww + gx;
        #pragma unroll
        for (int c = 0; c < 19; ++c) v[c] = s[(size_t)c * HW];
        v[19] = 0.0f;
    };
    auto write_entry = [&](int idx, const float v[20], int l) {
        sl[idx] = l;
        float4* dst = reinterpret_cast<float4*>(&sv[idx * CS]);
        dst[0] = make_float4(v[0],  v[1],  v[2],  v[3]);
        dst[1] = make_float4(v[4],  v[5],  v[6],  v[7]);
        dst[2] = make_float4(v[8],  v[9],  v[10], v[11]);
        dst[3] = make_float4(v[12], v[13], v[14], v[15]);
        dst[4] = make_float4(v[16], v[17], v[18], v[19]);
    };

    // compute this thread's weighted loss sum for current LDS contents
    auto compute_tile = [&]() -> float {
        const float4* P = reinterpret_cast<const float4*>(&sv[ep * CS]);
        const float4 p0 = P[0], p1 = P[1], p2 = P[2], p3 = P[3], p4 = P[4];
        const int lp = sl[ep];
        const bool vp = (lp != IGNORE_INDEX);

        auto dot19 = [&](float4 b0, float4 b1, float4 b2, float4 b3, float4 b4) {
            float xa = p0.x * b0.x, xb = p0.y * b0.y;
            xa = fmaf(p0.z, b0.z, xa); xb = fmaf(p0.w, b0.w, xb);
            xa = fmaf(p1.x, b1.x, xa); xb = fmaf(p1.y, b1.y, xb);
            xa = fmaf(p1.z, b1.z, xa); xb = fmaf(p1.w, b1.w, xb);
            xa = fmaf(p2.x, b2.x, xa); xb = fmaf(p2.y, b2.y, xb);
            xa = fmaf(p2.z, b2.z, xa); xb = fmaf(p2.w, b2.w, xb);
            xa = fmaf(p3.x, b3.x, xa); xb = fmaf(p3.y, b3.y, xb);
            xa = fmaf(p3.z, b3.z, xa); xb = fmaf(p3.w, b3.w, xb);
            xa = fmaf(p4.x, b4.x, xa); xb = fmaf(p4.y, b4.y, xb);
            xa = fmaf(p4.z, b4.z, xa);
            return xa + xb;
        };

        float ts;
        {   // diagonal (b == p): weight my[0]*mx[0] = 0.5*myf[0]*mxf2[2]
            float xd = dot19(p0, p1, p2, p3, p4);
            float t = vp ? -xd : xd;
            ts = (0.5f * myf[0] * mxf2[2]) * softplus(t);
        }
        const int DY[12] = {0, 0, 1, 1, 1, 1, 1, 2, 2, 2, 2, 2};
        const int DX[12] = {1, 2, -2, -1, 0, 1, 2, -2, -1, 0, 1, 2};
        #pragma unroll
        for (int dd = 0; dd < 12; dd += 2) {
            const int dy0 = DY[dd], dx0 = DX[dd];
            const int dy1 = DY[dd + 1], dx1 = DX[dd + 1];
            const int eq0 = (ty + dy0) * LXX + (tx + 2 + dx0);
            const int eq1 = (ty + dy1) * LXX + (tx + 2 + dx1);
            const float4* Q0 = reinterpret_cast<const float4*>(&sv[eq0 * CS]);
            const float4* Q1 = reinterpret_cast<const float4*>(&sv[eq1 * CS]);
            float4 a0 = Q0[0], a1 = Q0[1], a2 = Q0[2], a3 = Q0[3], a4 = Q0[4];
            float4 c0 = Q1[0], c1 = Q1[1], c2 = Q1[2], c3 = Q1[3], c4 = Q1[4];
            const int lq0 = sl[eq0], lq1 = sl[eq1];
            const float x0 = dot19(a0, a1, a2, a3, a4);
            const float x1 = dot19(c0, c1, c2, c3, c4);
            const float t0 = (vp && lq0 == lp) ? -x0 : x0;
            const float t1 = (vp && lq1 == lp) ? -x1 : x1;
            ts = fmaf(myf[dy0] * mxf2[dx0 + 2], softplus(t0), ts);
            ts = fmaf(myf[dy1] * mxf2[dx1 + 2], softplus(t1), ts);
        }
        return ts;
    };

    // ---- pipeline ----------------------------------------------------------
    float va[20], vb[20]; int la, lb;

    // stage n0
    load_entry(logits, labels, e0, va, la);
    if (has2) load_entry(logits, labels, e1, vb, lb);
    write_entry(e0, va, la);
    if (has2) write_entry(e1, vb, lb);
    __syncthreads();

    // issue n1 loads (latency hides under n0 compute)
    const float* img1 = logits + (size_t)Cc * HW;
    const int*   lab1 = labels + HW;
    load_entry(img1, lab1, e0, va, la);
    if (has2) load_entry(img1, lab1, e1, vb, lb);
    __builtin_amdgcn_sched_barrier(0);   // keep loads issued before compute

    float tsum = compute_tile();         // n0

    __syncthreads();                     // all waves done reading n0 LDS
    write_entry(e0, va, la);
    if (has2) write_entry(e1, vb, lb);
    __syncthreads();

    tsum += compute_tile();              // n1

    // reduce: f32 wave shuffle -> LDS -> one double store per block
    for (int off = 32; off > 0; off >>= 1) tsum += __shfl_down(tsum, off, 64);
    if ((tid & 63) == 0) sred[tid >> 6] = tsum;
    __syncthreads();
    if (tid == 0) {
        double s = 0.0;
        #pragma unroll
        for (int i = 0; i < NT / 64; ++i) s += (double)sred[i];
        partial[bid] = s;
    }
}

__global__ __launch_bounds__(256) void finalize_kernel(
        const double* __restrict__ partial, float* __restrict__ out) {
    __shared__ double sred[4];
    const int tid = threadIdx.x;
    double s = 0.0;
    for (int i = tid; i < NBLK; i += 256) s += partial[i];
    for (int off = 32; off > 0; off >>= 1) s += __shfl_down(s, off, 64);
    if ((tid & 63) == 0) sred[tid >> 6] = s;
    __syncthreads();
    if (tid == 0) {
        // mean over n*9*9*L = 2*81*382*382 = 23,639,688 terms
        double tot = sred[0] + sred[1] + sred[2] + sred[3];
        out[0] = (float)(tot * (1.0 / 23639688.0));
    }
}

extern "C" void kernel_launch(void* const* d_in, const int* in_sizes, int n_in,
                              void* d_out, int out_size, void* d_ws, size_t ws_size,
                              hipStream_t stream) {
    const float* logits = (const float*)d_in[0];
    const int*   labels = (const int*)d_in[1];
    float* out = (float*)d_out;
    double* partial = (double*)d_ws;   // NBLK doubles, written unconditionally

    aff_loss_kernel<<<dim3(NBLK), dim3(NT), 0, stream>>>(logits, labels, partial);
    finalize_kernel<<<1, 256, 0, stream>>>(partial, out);
}